// Round 1
// 451.315 us; speedup vs baseline: 1.3125x; 1.3125x over previous
//
#include <hip/hip_runtime.h>

// Problem constants: B=16, C=64, H=128, W=128, bchw layout, HW = 16384
// Output: fp32. Q/K/V staged as bf16 in ws. Attention via mfma_f32_16x16x32_bf16.
// Projections via mfma_f32_16x16x32_f16 (fp16 inputs, fp32 accum).
#define HW 16384
#define NE 16777216ull   // B*C*H*W

typedef short bf16x8 __attribute__((ext_vector_type(8)));
typedef _Float16 f16x8 __attribute__((ext_vector_type(8)));
typedef float f32x4  __attribute__((ext_vector_type(4)));

__device__ __forceinline__ unsigned short f2bf(float f) {
    unsigned int u = __float_as_uint(f);
    unsigned int r = (u + 0x7FFFu + ((u >> 16) & 1u)) >> 16;  // RNE
    return (unsigned short)r;
}
__device__ __forceinline__ float bf2f(unsigned short s) {
    return __uint_as_float(((unsigned int)s) << 16);
}

__global__ __launch_bounds__(128)
void zero_stats_kernel(float* __restrict__ stats) {
    stats[threadIdx.x] = 0.f;
}

// MFMA projection: out[b,o,hw] = bf16( sum_c w[o,c] * in[b,c,hw] + bias[o] )
// One block = one b, 256-wide hw tile. 256 threads = 4 waves; wave wv owns
// output rows [16wv, 16wv+16).
// LDS: xT[n][c] fp16 (transposed tile), XOR-chunk swizzled:
//   chunk kc (8 halves) of row n stored at n*64 + ((kc ^ (n&7)) * 8).
// Transpose is free: thread t reads column hw0+t along c (coalesced across
// lanes), packs 8 halves, one ds_write_b128 per chunk.
// If w2 != null, also computes out2 from the same staged tile (K+V fusion:
// x is read from HBM once for both).
__global__ __launch_bounds__(256)
void proj_mfma_kernel(const float* __restrict__ in,
                      const float* __restrict__ w1, const float* __restrict__ b1,
                      unsigned short* __restrict__ out1,
                      const float* __restrict__ w2, const float* __restrict__ b2,
                      unsigned short* __restrict__ out2) {
    __shared__ __align__(16) _Float16 xT[256 * 64];  // 32 KB
    int tid = threadIdx.x;
    int pbase = blockIdx.x * 256;
    int b = pbase >> 14;
    int hw0 = pbase & 16383;
    const float* inb = in + (size_t)b * (64 * HW);

    // ---- stage transposed tile: thread t owns column n = t ----
    {
        int n = tid;
        int swz = n & 7;
        const float* colp = inb + hw0 + n;
#pragma unroll
        for (int kc = 0; kc < 8; ++kc) {
            f16x8 ev;
#pragma unroll
            for (int j = 0; j < 8; ++j)
                ev[j] = (_Float16)colp[(kc * 8 + j) * HW];
            *reinterpret_cast<f16x8*>(&xT[n * 64 + ((kc ^ swz) * 8)]) = ev;
        }
    }

    int lane = tid & 63;
    int wv = tid >> 6;
    int quad = lane >> 4;
    int m16 = lane & 15;
    int mb = wv * 16;
    int sw = m16 & 7;
    int hasw2 = (w2 != nullptr);

    // ---- A-frags (weights, fp16) + bias; lane (quad,m16) holds
    //      W[mb+m16][(ks*4+quad)*8 .. +8]  (overlaps with staging latency) ----
    f16x8 a1[2], a2[2];
    float bias1[4], bias2[4];
#pragma unroll
    for (int ks = 0; ks < 2; ++ks) {
        const float* wr = w1 + (mb + m16) * 64 + (ks * 4 + quad) * 8;
        f16x8 ev;
#pragma unroll
        for (int j = 0; j < 8; ++j) ev[j] = (_Float16)wr[j];
        a1[ks] = ev;
    }
#pragma unroll
    for (int r = 0; r < 4; ++r) bias1[r] = b1[mb + quad * 4 + r];
    if (hasw2) {
#pragma unroll
        for (int ks = 0; ks < 2; ++ks) {
            const float* wr = w2 + (mb + m16) * 64 + (ks * 4 + quad) * 8;
            f16x8 ev;
#pragma unroll
            for (int j = 0; j < 8; ++j) ev[j] = (_Float16)wr[j];
            a2[ks] = ev;
        }
#pragma unroll
        for (int r = 0; r < 4; ++r) bias2[r] = b2[mb + quad * 4 + r];
    }
    __syncthreads();

    unsigned short* o1 = out1 + (size_t)b * (64 * HW);
    unsigned short* o2 = hasw2 ? (out2 + (size_t)b * (64 * HW)) : out1;

    // ---- D[o][n] = sum_c W[o][c] * xT[n][c] ; C/D: col=lane&15, row=quad*4+r ----
#pragma unroll
    for (int nt = 0; nt < 16; ++nt) {
        int row = nt * 16 + m16;
        f16x8 bF0 = *reinterpret_cast<const f16x8*>(&xT[row * 64 + ((quad ^ sw) * 8)]);
        f16x8 bF1 = *reinterpret_cast<const f16x8*>(&xT[row * 64 + (((4 + quad) ^ sw) * 8)]);
        f32x4 acc1 = {bias1[0], bias1[1], bias1[2], bias1[3]};
        acc1 = __builtin_amdgcn_mfma_f32_16x16x32_f16(a1[0], bF0, acc1, 0, 0, 0);
        acc1 = __builtin_amdgcn_mfma_f32_16x16x32_f16(a1[1], bF1, acc1, 0, 0, 0);
        int cbase = (mb + quad * 4) * HW + hw0 + nt * 16 + m16;
#pragma unroll
        for (int r = 0; r < 4; ++r)
            o1[cbase + r * HW] = f2bf(acc1[r]);
        if (hasw2) {
            f32x4 acc2 = {bias2[0], bias2[1], bias2[2], bias2[3]};
            acc2 = __builtin_amdgcn_mfma_f32_16x16x32_f16(a2[0], bF0, acc2, 0, 0, 0);
            acc2 = __builtin_amdgcn_mfma_f32_16x16x32_f16(a2[1], bF1, acc2, 0, 0, 0);
#pragma unroll
            for (int r = 0; r < 4; ++r)
                o2[cbase + r * HW] = f2bf(acc2[r]);
        }
    }
}

// MFMA attention. One block (512 thr = 8 waves) per (b,c).
// LDS: bufA (Q then P), bufB (K then Vt), each 128x128 bf16, XOR-chunk swizzle:
// element (row, k) stored at row*128 + ((k>>3) ^ (row&7))*8 + (k&7).
// Frag reads (A and B patterns) are then conflict-free ds_read_b128.
__global__ __launch_bounds__(512, 4)
void attn_kernel(const unsigned short* __restrict__ Q, const unsigned short* __restrict__ K,
                 const unsigned short* __restrict__ V, float* __restrict__ io,
                 float* __restrict__ stats, int accumulate) {
    __shared__ short bufA[16384];  // 32 KB
    __shared__ short bufB[16384];  // 32 KB
    int bc = blockIdx.x;
    size_t base = (size_t)bc * HW;
    int tid = threadIdx.x;
    int lane = tid & 63;
    int wv = tid >> 6;         // wave -> row strip [16wv, 16wv+16)
    int quad = lane >> 4;
    int m16 = lane & 15;

    // ---- Preload V into registers (overlaps with QK^T latency) ----
    uint4 vreg[4];
    {
        int g0 = tid >> 4;          // 0..31
        int w0 = (tid & 15) * 8;
#pragma unroll
        for (int i = 0; i < 4; ++i)
            vreg[i] = *(const uint4*)(V + base + (size_t)(g0 + 32 * i) * 128 + w0);
    }

    // ---- Stage Q -> bufA, K -> bufB (swizzled) ----
    {
        int r0 = tid >> 4;          // 0..31
        int c0 = tid & 15;          // chunk
#pragma unroll
        for (int i = 0; i < 4; ++i) {
            int r = r0 + 32 * i;
            uint4 q = *(const uint4*)(Q + base + (size_t)r * 128 + c0 * 8);
            uint4 k = *(const uint4*)(K + base + (size_t)r * 128 + c0 * 8);
            int ch = c0 ^ (r & 7);
            *reinterpret_cast<uint4*>(&bufA[r * 128 + ch * 8]) = q;
            *reinterpret_cast<uint4*>(&bufB[r * 128 + ch * 8]) = k;
        }
    }
    __syncthreads();

    // ---- S = Q K^T : A-frags from bufA (own strip), B-frags from bufB ----
    int rowA = wv * 16 + m16;
    int sw = m16 & 7;  // rowA&7 == (16n+m16)&7 == m16&7 for all tiles
    bf16x8 aF[4];
#pragma unroll
    for (int ks = 0; ks < 4; ++ks) {
        int ch = (ks * 4 + quad) ^ sw;
        aF[ks] = *reinterpret_cast<const bf16x8*>(&bufA[rowA * 128 + ch * 8]);
    }
    f32x4 sacc[8];
#pragma unroll
    for (int n = 0; n < 8; ++n) {
        f32x4 acc = {0.f, 0.f, 0.f, 0.f};
        int rowB = n * 16 + m16;
#pragma unroll
        for (int ks = 0; ks < 4; ++ks) {
            int ch = (ks * 4 + quad) ^ sw;
            bf16x8 bF = *reinterpret_cast<const bf16x8*>(&bufB[rowB * 128 + ch * 8]);
            acc = __builtin_amdgcn_mfma_f32_16x16x32_bf16(aF[ks], bF, acc, 0, 0, 0);
        }
        sacc[n] = acc;
    }

    // ---- softmax over g (cols), rows live in regs: row = 16wv + quad*4 + r ----
    const float scale = 0.08838834764831845f;  // 1/sqrt(128)
    float mx[4] = {-3.4e38f, -3.4e38f, -3.4e38f, -3.4e38f};
#pragma unroll
    for (int n = 0; n < 8; ++n)
#pragma unroll
        for (int r = 0; r < 4; ++r) {
            sacc[n][r] *= scale;
            mx[r] = fmaxf(mx[r], sacc[n][r]);
        }
#pragma unroll
    for (int mask = 8; mask >= 1; mask >>= 1)
#pragma unroll
        for (int r = 0; r < 4; ++r) mx[r] = fmaxf(mx[r], __shfl_xor(mx[r], mask));
    float sum[4] = {0.f, 0.f, 0.f, 0.f};
#pragma unroll
    for (int n = 0; n < 8; ++n)
#pragma unroll
        for (int r = 0; r < 4; ++r) {
            float e = __expf(sacc[n][r] - mx[r]);
            sacc[n][r] = e;
            sum[r] += e;
        }
#pragma unroll
    for (int mask = 8; mask >= 1; mask >>= 1)
#pragma unroll
        for (int r = 0; r < 4; ++r) sum[r] += __shfl_xor(sum[r], mask);
    float inv[4];
#pragma unroll
    for (int r = 0; r < 4; ++r) inv[r] = 1.0f / sum[r];

    // ---- write P (bf16) into bufA over Q (wave-private strip; no barrier) ----
#pragma unroll
    for (int n = 0; n < 8; ++n)
#pragma unroll
        for (int r = 0; r < 4; ++r) {
            int row = wv * 16 + quad * 4 + r;
            int col = n * 16 + m16;
            int pos = row * 128 + (((col >> 3) ^ (row & 7)) * 8) + (col & 7);
            bufA[pos] = (short)f2bf(sacc[n][r] * inv[r]);
        }

    __syncthreads();  // all K B-frag reads done -> safe to overwrite bufB

    // ---- Vt (transposed, swizzled) into bufB from vreg ----
    {
        int g0 = tid >> 4;
        int w0 = (tid & 15) * 8;
#pragma unroll
        for (int i = 0; i < 4; ++i) {
            int g = g0 + 32 * i;
            unsigned short e[8];
            *(uint4*)e = vreg[i];
#pragma unroll
            for (int jj = 0; jj < 8; ++jj) {
                int j = jj ^ (tid & 7);  // stagger to break bank pile-up
                int w = w0 + j;
                int pos = w * 128 + (((g >> 3) ^ (w & 7)) * 8) + (g & 7);
                bufB[pos] = (short)e[j];
            }
        }
    }
    __syncthreads();

    // ---- O = P V : A-frags = P (bufA own strip), B-frags = Vt (bufB) ----
#pragma unroll
    for (int ks = 0; ks < 4; ++ks) {
        int ch = (ks * 4 + quad) ^ sw;
        aF[ks] = *reinterpret_cast<const bf16x8*>(&bufA[rowA * 128 + ch * 8]);
    }
    f32x4 oacc[8];
#pragma unroll
    for (int n = 0; n < 8; ++n) {
        f32x4 acc = {0.f, 0.f, 0.f, 0.f};
        int rowB = n * 16 + m16;
#pragma unroll
        for (int ks = 0; ks < 4; ++ks) {
            int ch = (ks * 4 + quad) ^ sw;
            bf16x8 bF = *reinterpret_cast<const bf16x8*>(&bufB[rowB * 128 + ch * 8]);
            acc = __builtin_amdgcn_mfma_f32_16x16x32_bf16(aF[ks], bF, acc, 0, 0, 0);
        }
        oacc[n] = acc;
    }

    // ---- epilogue: io (fp32) ; C layout: row = 16wv + quad*4 + r, col = 16n + m16
    if (!accumulate) {
#pragma unroll
        for (int n = 0; n < 8; ++n)
#pragma unroll
            for (int r = 0; r < 4; ++r) {
                int row = wv * 16 + quad * 4 + r;
                int col = n * 16 + m16;
                io[base + row * 128 + col] = oacc[n][r];
            }
    } else {
        float lsum = 0.f, lsq = 0.f;
#pragma unroll
        for (int n = 0; n < 8; ++n)
#pragma unroll
            for (int r = 0; r < 4; ++r) {
                int row = wv * 16 + quad * 4 + r;
                int col = n * 16 + m16;
                size_t idx = base + row * 128 + col;
                float f = io[idx] + oacc[n][r];
                io[idx] = f;
                lsum += f;
                lsq += f * f;
            }
#pragma unroll
        for (int mask = 32; mask >= 1; mask >>= 1) {
            lsum += __shfl_xor(lsum, mask);
            lsq  += __shfl_xor(lsq,  mask);
        }
        if (lane == 0) {
            int c = bc & 63;
            atomicAdd(&stats[c], lsum);
            atomicAdd(&stats[64 + c], lsq);
        }
    }
}

// in-place fp32: io = relu((io - mean) * rsqrt(var+eps) * gamma + beta)
__global__ __launch_bounds__(256)
void bn_relu_kernel(float* __restrict__ io, const float* __restrict__ stats,
                    const float* __restrict__ gamma, const float* __restrict__ beta) {
    int idx = blockIdx.x * 256 + threadIdx.x;
    int e = idx << 2;
    int c = (e >> 14) & 63;
    const float invN = 1.0f / 262144.0f;
    float mean = stats[c] * invN;
    float var = stats[64 + c] * invN - mean * mean;
    float k = rsqrtf(var + 1e-5f) * gamma[c];
    float bb = beta[c] - mean * k;
    float4 f = reinterpret_cast<const float4*>(io)[idx];
    float4 o;
    o.x = fmaxf(f.x * k + bb, 0.f);
    o.y = fmaxf(f.y * k + bb, 0.f);
    o.z = fmaxf(f.z * k + bb, 0.f);
    o.w = fmaxf(f.w * k + bb, 0.f);
    reinterpret_cast<float4*>(io)[idx] = o;
}

extern "C" void kernel_launch(void* const* d_in, const int* in_sizes, int n_in,
                              void* d_out, int out_size, void* d_ws, size_t ws_size,
                              hipStream_t stream) {
    const float* x1 = (const float*)d_in[0];
    const float* x2 = (const float*)d_in[1];
    const float* rssi1 = (const float*)d_in[2];
    const float* rssi2 = (const float*)d_in[3];
    const float* qw = (const float*)d_in[4];
    const float* qb = (const float*)d_in[5];
    const float* kw = (const float*)d_in[6];
    const float* kb = (const float*)d_in[7];
    const float* vw = (const float*)d_in[8];
    const float* vb = (const float*)d_in[9];
    const float* gamma = (const float*)d_in[10];
    const float* beta = (const float*)d_in[11];

    float* stats = (float*)d_ws;
    unsigned short* Q = (unsigned short*)((char*)d_ws + 512);
    unsigned short* K = Q + NE;
    unsigned short* V = K + NE;
    float* io = (float*)d_out;

    zero_stats_kernel<<<1, 128, 0, stream>>>(stats);

    // branch 1: Q from rssi1; K+V fused (x1 read once)
    proj_mfma_kernel<<<1024, 256, 0, stream>>>(rssi1, qw, qb, Q,
                                               nullptr, nullptr, nullptr);
    proj_mfma_kernel<<<1024, 256, 0, stream>>>(x1, kw, kb, K, vw, vb, V);
    attn_kernel<<<1024, 512, 0, stream>>>(Q, K, V, io, stats, 0);

    // branch 2
    proj_mfma_kernel<<<1024, 256, 0, stream>>>(rssi2, qw, qb, Q,
                                               nullptr, nullptr, nullptr);
    proj_mfma_kernel<<<1024, 256, 0, stream>>>(x2, kw, kb, K, vw, vb, V);
    attn_kernel<<<1024, 512, 0, stream>>>(Q, K, V, io, stats, 1);

    bn_relu_kernel<<<16384, 256, 0, stream>>>(io, stats, gamma, beta);
}

// Round 2
// 443.533 us; speedup vs baseline: 1.3356x; 1.0175x over previous
//
#include <hip/hip_runtime.h>

// Problem constants: B=16, C=64, H=128, W=128, bchw layout, HW = 16384
// Output: fp32. Q/K/V staged as bf16 in ws. Attention via mfma_f32_16x16x32_bf16.
// Projections via mfma_f32_16x16x32_f16 (fp16 inputs, fp32 accum), with an
// LDS round-trip epilogue so global stores are 16B coalesced (1KB/wave-instr).
#define HW 16384
#define NE 16777216ull   // B*C*H*W

typedef short bf16x8 __attribute__((ext_vector_type(8)));
typedef _Float16 f16x8 __attribute__((ext_vector_type(8)));
typedef float f32x4  __attribute__((ext_vector_type(4)));

__device__ __forceinline__ unsigned short f2bf(float f) {
    unsigned int u = __float_as_uint(f);
    unsigned int r = (u + 0x7FFFu + ((u >> 16) & 1u)) >> 16;  // RNE
    return (unsigned short)r;
}

// MFMA projection: out[b,o,hw] = bf16( sum_c w[o,c] * in[b,c,hw] + bias[o] )
// One block = one b, 256-wide hw tile. 256 threads = 4 waves; wave wv owns
// output rows [16wv, 16wv+16).
// LDS xT[n][c] fp16 (transposed input tile), XOR-chunk swizzled; after MFMA the
// same 32KB is reused as obuf[64][256] bf16 (chunk-of-8 XOR swizzle) so the
// final global stores are dwordx4, two 512B segments per wave-instruction.
// If w2 != null, also computes out2 from the same staged tile (K+V fusion).
// If stats != null, block 0 zeroes stats[0..127] (replaces zero_stats kernel).
__global__ __launch_bounds__(256)
void proj_mfma_kernel(const float* __restrict__ in,
                      const float* __restrict__ w1, const float* __restrict__ b1,
                      unsigned short* __restrict__ out1,
                      const float* __restrict__ w2, const float* __restrict__ b2,
                      unsigned short* __restrict__ out2,
                      float* __restrict__ stats) {
    __shared__ __align__(16) _Float16 xT[256 * 64];  // 32 KB
    unsigned short* obuf = reinterpret_cast<unsigned short*>(xT);
    int tid = threadIdx.x;
    if (stats != nullptr && blockIdx.x == 0 && tid < 128) stats[tid] = 0.f;
    int pbase = blockIdx.x * 256;
    int b = pbase >> 14;
    int hw0 = pbase & 16383;
    const float* inb = in + (size_t)b * (64 * HW);

    // ---- stage transposed tile: thread t owns column n = t ----
    {
        int n = tid;
        int swz = n & 7;
        const float* colp = inb + hw0 + n;
#pragma unroll
        for (int kc = 0; kc < 8; ++kc) {
            f16x8 ev;
#pragma unroll
            for (int j = 0; j < 8; ++j)
                ev[j] = (_Float16)colp[(kc * 8 + j) * HW];
            *reinterpret_cast<f16x8*>(&xT[n * 64 + ((kc ^ swz) * 8)]) = ev;
        }
    }

    int lane = tid & 63;
    int wv = tid >> 6;
    int quad = lane >> 4;
    int m16 = lane & 15;
    int mb = wv * 16;
    int sw = m16 & 7;
    int hasw2 = (w2 != nullptr);

    // ---- A-frags (weights, fp16) + bias (overlaps with staging latency) ----
    f16x8 a1[2], a2[2];
    float bias1[4], bias2[4];
#pragma unroll
    for (int ks = 0; ks < 2; ++ks) {
        const float* wr = w1 + (mb + m16) * 64 + (ks * 4 + quad) * 8;
        f16x8 ev;
#pragma unroll
        for (int j = 0; j < 8; ++j) ev[j] = (_Float16)wr[j];
        a1[ks] = ev;
    }
#pragma unroll
    for (int r = 0; r < 4; ++r) bias1[r] = b1[mb + quad * 4 + r];
    if (hasw2) {
#pragma unroll
        for (int ks = 0; ks < 2; ++ks) {
            const float* wr = w2 + (mb + m16) * 64 + (ks * 4 + quad) * 8;
            f16x8 ev;
#pragma unroll
            for (int j = 0; j < 8; ++j) ev[j] = (_Float16)wr[j];
            a2[ks] = ev;
        }
#pragma unroll
        for (int r = 0; r < 4; ++r) bias2[r] = b2[mb + quad * 4 + r];
    }
    __syncthreads();

    unsigned short* o1 = out1 + (size_t)b * (64 * HW);
    unsigned short* o2 = hasw2 ? (out2 + (size_t)b * (64 * HW)) : out1;

    // ---- D[o][n] = sum_c W[o][c] * xT[n][c]; results packed to bf16 pairs ----
    unsigned int pk1[32], pk2[32];
#pragma unroll
    for (int nt = 0; nt < 16; ++nt) {
        int row = nt * 16 + m16;
        f16x8 bF0 = *reinterpret_cast<const f16x8*>(&xT[row * 64 + ((quad ^ sw) * 8)]);
        f16x8 bF1 = *reinterpret_cast<const f16x8*>(&xT[row * 64 + (((4 + quad) ^ sw) * 8)]);
        f32x4 acc1 = {bias1[0], bias1[1], bias1[2], bias1[3]};
        acc1 = __builtin_amdgcn_mfma_f32_16x16x32_f16(a1[0], bF0, acc1, 0, 0, 0);
        acc1 = __builtin_amdgcn_mfma_f32_16x16x32_f16(a1[1], bF1, acc1, 0, 0, 0);
        pk1[nt * 2 + 0] = (unsigned int)f2bf(acc1[0]) | ((unsigned int)f2bf(acc1[1]) << 16);
        pk1[nt * 2 + 1] = (unsigned int)f2bf(acc1[2]) | ((unsigned int)f2bf(acc1[3]) << 16);
        if (hasw2) {
            f32x4 acc2 = {bias2[0], bias2[1], bias2[2], bias2[3]};
            acc2 = __builtin_amdgcn_mfma_f32_16x16x32_f16(a2[0], bF0, acc2, 0, 0, 0);
            acc2 = __builtin_amdgcn_mfma_f32_16x16x32_f16(a2[1], bF1, acc2, 0, 0, 0);
            pk2[nt * 2 + 0] = (unsigned int)f2bf(acc2[0]) | ((unsigned int)f2bf(acc2[1]) << 16);
            pk2[nt * 2 + 1] = (unsigned int)f2bf(acc2[2]) | ((unsigned int)f2bf(acc2[3]) << 16);
        }
    }
    __syncthreads();  // all xT B-frag reads done -> safe to overwrite as obuf

    // ---- pass 1: scatter pk1 into obuf[64][256] (chunk XOR swizzle), then
    //      coalesced dwordx4 stores to out1 ----
#pragma unroll
    for (int nt = 0; nt < 16; ++nt)
#pragma unroll
        for (int r = 0; r < 4; ++r) {
            int row = mb + quad * 4 + r;
            int col = nt * 16 + m16;
            unsigned int v = pk1[nt * 2 + (r >> 1)];
            unsigned short e = (r & 1) ? (unsigned short)(v >> 16) : (unsigned short)(v & 0xffff);
            obuf[row * 256 + (((col >> 3) ^ (row & 7)) * 8) + (col & 7)] = e;
        }
    __syncthreads();
#pragma unroll
    for (int k = 0; k < 8; ++k) {
        int c = k * 256 + tid;
        int row = c >> 5;
        int cg = c & 31;
        uint4 v = *reinterpret_cast<const uint4*>(&obuf[row * 256 + ((cg ^ (row & 7)) * 8)]);
        *reinterpret_cast<uint4*>(&o1[(size_t)row * HW + hw0 + cg * 8]) = v;
    }

    if (hasw2) {
        __syncthreads();
#pragma unroll
        for (int nt = 0; nt < 16; ++nt)
#pragma unroll
            for (int r = 0; r < 4; ++r) {
                int row = mb + quad * 4 + r;
                int col = nt * 16 + m16;
                unsigned int v = pk2[nt * 2 + (r >> 1)];
                unsigned short e = (r & 1) ? (unsigned short)(v >> 16) : (unsigned short)(v & 0xffff);
                obuf[row * 256 + (((col >> 3) ^ (row & 7)) * 8) + (col & 7)] = e;
            }
        __syncthreads();
#pragma unroll
        for (int k = 0; k < 8; ++k) {
            int c = k * 256 + tid;
            int row = c >> 5;
            int cg = c & 31;
            uint4 v = *reinterpret_cast<const uint4*>(&obuf[row * 256 + ((cg ^ (row & 7)) * 8)]);
            *reinterpret_cast<uint4*>(&o2[(size_t)row * HW + hw0 + cg * 8]) = v;
        }
    }
}

// MFMA attention. One block (512 thr = 8 waves) per (b,c).
// LDS: bufA (Q then P), bufB (K then Vt), each 128x128 bf16, XOR-chunk swizzle:
// element (row, k) stored at row*128 + ((k>>3) ^ (row&7))*8 + (k&7).
// Frag reads (A and B patterns) are then conflict-free ds_read_b128.
__global__ __launch_bounds__(512, 4)
void attn_kernel(const unsigned short* __restrict__ Q, const unsigned short* __restrict__ K,
                 const unsigned short* __restrict__ V, float* __restrict__ io,
                 float* __restrict__ stats, int accumulate) {
    __shared__ short bufA[16384];  // 32 KB
    __shared__ short bufB[16384];  // 32 KB
    int bc = blockIdx.x;
    size_t base = (size_t)bc * HW;
    int tid = threadIdx.x;
    int lane = tid & 63;
    int wv = tid >> 6;         // wave -> row strip [16wv, 16wv+16)
    int quad = lane >> 4;
    int m16 = lane & 15;

    // ---- Preload V into registers (overlaps with QK^T latency) ----
    uint4 vreg[4];
    {
        int g0 = tid >> 4;          // 0..31
        int w0 = (tid & 15) * 8;
#pragma unroll
        for (int i = 0; i < 4; ++i)
            vreg[i] = *(const uint4*)(V + base + (size_t)(g0 + 32 * i) * 128 + w0);
    }

    // ---- Stage Q -> bufA, K -> bufB (swizzled) ----
    {
        int r0 = tid >> 4;          // 0..31
        int c0 = tid & 15;          // chunk
#pragma unroll
        for (int i = 0; i < 4; ++i) {
            int r = r0 + 32 * i;
            uint4 q = *(const uint4*)(Q + base + (size_t)r * 128 + c0 * 8);
            uint4 k = *(const uint4*)(K + base + (size_t)r * 128 + c0 * 8);
            int ch = c0 ^ (r & 7);
            *reinterpret_cast<uint4*>(&bufA[r * 128 + ch * 8]) = q;
            *reinterpret_cast<uint4*>(&bufB[r * 128 + ch * 8]) = k;
        }
    }
    __syncthreads();

    // ---- S = Q K^T : A-frags from bufA (own strip), B-frags from bufB ----
    int rowA = wv * 16 + m16;
    int sw = m16 & 7;  // rowA&7 == (16n+m16)&7 == m16&7 for all tiles
    bf16x8 aF[4];
#pragma unroll
    for (int ks = 0; ks < 4; ++ks) {
        int ch = (ks * 4 + quad) ^ sw;
        aF[ks] = *reinterpret_cast<const bf16x8*>(&bufA[rowA * 128 + ch * 8]);
    }
    f32x4 sacc[8];
#pragma unroll
    for (int n = 0; n < 8; ++n) {
        f32x4 acc = {0.f, 0.f, 0.f, 0.f};
        int rowB = n * 16 + m16;
#pragma unroll
        for (int ks = 0; ks < 4; ++ks) {
            int ch = (ks * 4 + quad) ^ sw;
            bf16x8 bF = *reinterpret_cast<const bf16x8*>(&bufB[rowB * 128 + ch * 8]);
            acc = __builtin_amdgcn_mfma_f32_16x16x32_bf16(aF[ks], bF, acc, 0, 0, 0);
        }
        sacc[n] = acc;
    }

    // ---- softmax over g (cols), rows live in regs: row = 16wv + quad*4 + r ----
    const float scale = 0.08838834764831845f;  // 1/sqrt(128)
    float mx[4] = {-3.4e38f, -3.4e38f, -3.4e38f, -3.4e38f};
#pragma unroll
    for (int n = 0; n < 8; ++n)
#pragma unroll
        for (int r = 0; r < 4; ++r) {
            sacc[n][r] *= scale;
            mx[r] = fmaxf(mx[r], sacc[n][r]);
        }
#pragma unroll
    for (int mask = 8; mask >= 1; mask >>= 1)
#pragma unroll
        for (int r = 0; r < 4; ++r) mx[r] = fmaxf(mx[r], __shfl_xor(mx[r], mask));
    float sum[4] = {0.f, 0.f, 0.f, 0.f};
#pragma unroll
    for (int n = 0; n < 8; ++n)
#pragma unroll
        for (int r = 0; r < 4; ++r) {
            float e = __expf(sacc[n][r] - mx[r]);
            sacc[n][r] = e;
            sum[r] += e;
        }
#pragma unroll
    for (int mask = 8; mask >= 1; mask >>= 1)
#pragma unroll
        for (int r = 0; r < 4; ++r) sum[r] += __shfl_xor(sum[r], mask);
    float inv[4];
#pragma unroll
    for (int r = 0; r < 4; ++r) inv[r] = 1.0f / sum[r];

    // ---- write P (bf16) into bufA over Q (wave-private strip; no barrier) ----
#pragma unroll
    for (int n = 0; n < 8; ++n)
#pragma unroll
        for (int r = 0; r < 4; ++r) {
            int row = wv * 16 + quad * 4 + r;
            int col = n * 16 + m16;
            int pos = row * 128 + (((col >> 3) ^ (row & 7)) * 8) + (col & 7);
            bufA[pos] = (short)f2bf(sacc[n][r] * inv[r]);
        }

    __syncthreads();  // all K B-frag reads done -> safe to overwrite bufB

    // ---- prefetch io for the accumulate RMW (hidden under Vt staging + PV) ----
    float iopre[8][4];
    if (accumulate) {
#pragma unroll
        for (int n = 0; n < 8; ++n)
#pragma unroll
            for (int r = 0; r < 4; ++r)
                iopre[n][r] = io[base + (wv * 16 + quad * 4 + r) * 128 + n * 16 + m16];
    }

    // ---- Vt (transposed, swizzled) into bufB from vreg ----
    {
        int g0 = tid >> 4;
        int w0 = (tid & 15) * 8;
#pragma unroll
        for (int i = 0; i < 4; ++i) {
            int g = g0 + 32 * i;
            unsigned short e[8];
            *(uint4*)e = vreg[i];
#pragma unroll
            for (int jj = 0; jj < 8; ++jj) {
                int j = jj ^ (tid & 7);  // stagger to break bank pile-up
                int w = w0 + j;
                int pos = w * 128 + (((g >> 3) ^ (w & 7)) * 8) + (g & 7);
                bufB[pos] = (short)e[j];
            }
        }
    }
    __syncthreads();

    // ---- O = P V : A-frags = P (bufA own strip), B-frags = Vt (bufB) ----
#pragma unroll
    for (int ks = 0; ks < 4; ++ks) {
        int ch = (ks * 4 + quad) ^ sw;
        aF[ks] = *reinterpret_cast<const bf16x8*>(&bufA[rowA * 128 + ch * 8]);
    }
    f32x4 oacc[8];
#pragma unroll
    for (int n = 0; n < 8; ++n) {
        f32x4 acc = {0.f, 0.f, 0.f, 0.f};
        int rowB = n * 16 + m16;
#pragma unroll
        for (int ks = 0; ks < 4; ++ks) {
            int ch = (ks * 4 + quad) ^ sw;
            bf16x8 bF = *reinterpret_cast<const bf16x8*>(&bufB[rowB * 128 + ch * 8]);
            acc = __builtin_amdgcn_mfma_f32_16x16x32_bf16(aF[ks], bF, acc, 0, 0, 0);
        }
        oacc[n] = acc;
    }

    // ---- epilogue: io (fp32) ; C layout: row = 16wv + quad*4 + r, col = 16n + m16
    if (!accumulate) {
#pragma unroll
        for (int n = 0; n < 8; ++n)
#pragma unroll
            for (int r = 0; r < 4; ++r) {
                int row = wv * 16 + quad * 4 + r;
                int col = n * 16 + m16;
                io[base + row * 128 + col] = oacc[n][r];
            }
    } else {
        float lsum = 0.f, lsq = 0.f;
#pragma unroll
        for (int n = 0; n < 8; ++n)
#pragma unroll
            for (int r = 0; r < 4; ++r) {
                int row = wv * 16 + quad * 4 + r;
                int col = n * 16 + m16;
                size_t idx = base + row * 128 + col;
                float f = iopre[n][r] + oacc[n][r];
                io[idx] = f;
                lsum += f;
                lsq += f * f;
            }
#pragma unroll
        for (int mask = 32; mask >= 1; mask >>= 1) {
            lsum += __shfl_xor(lsum, mask);
            lsq  += __shfl_xor(lsq,  mask);
        }
        if (lane == 0) {
            int c = bc & 63;
            atomicAdd(&stats[c], lsum);
            atomicAdd(&stats[64 + c], lsq);
        }
    }
}

// in-place fp32: io = relu((io - mean) * rsqrt(var+eps) * gamma + beta)
__global__ __launch_bounds__(256)
void bn_relu_kernel(float* __restrict__ io, const float* __restrict__ stats,
                    const float* __restrict__ gamma, const float* __restrict__ beta) {
    int idx = blockIdx.x * 256 + threadIdx.x;
    int e = idx << 2;
    int c = (e >> 14) & 63;
    const float invN = 1.0f / 262144.0f;
    float mean = stats[c] * invN;
    float var = stats[64 + c] * invN - mean * mean;
    float k = rsqrtf(var + 1e-5f) * gamma[c];
    float bb = beta[c] - mean * k;
    float4 f = reinterpret_cast<const float4*>(io)[idx];
    float4 o;
    o.x = fmaxf(f.x * k + bb, 0.f);
    o.y = fmaxf(f.y * k + bb, 0.f);
    o.z = fmaxf(f.z * k + bb, 0.f);
    o.w = fmaxf(f.w * k + bb, 0.f);
    reinterpret_cast<float4*>(io)[idx] = o;
}

extern "C" void kernel_launch(void* const* d_in, const int* in_sizes, int n_in,
                              void* d_out, int out_size, void* d_ws, size_t ws_size,
                              hipStream_t stream) {
    const float* x1 = (const float*)d_in[0];
    const float* x2 = (const float*)d_in[1];
    const float* rssi1 = (const float*)d_in[2];
    const float* rssi2 = (const float*)d_in[3];
    const float* qw = (const float*)d_in[4];
    const float* qb = (const float*)d_in[5];
    const float* kw = (const float*)d_in[6];
    const float* kb = (const float*)d_in[7];
    const float* vw = (const float*)d_in[8];
    const float* vb = (const float*)d_in[9];
    const float* gamma = (const float*)d_in[10];
    const float* beta = (const float*)d_in[11];

    float* stats = (float*)d_ws;
    unsigned short* Q = (unsigned short*)((char*)d_ws + 512);
    unsigned short* K = Q + NE;
    unsigned short* V = K + NE;
    float* io = (float*)d_out;

    // branch 1: Q from rssi1 (also zeroes stats); K+V fused (x1 read once)
    proj_mfma_kernel<<<1024, 256, 0, stream>>>(rssi1, qw, qb, Q,
                                               nullptr, nullptr, nullptr, stats);
    proj_mfma_kernel<<<1024, 256, 0, stream>>>(x1, kw, kb, K, vw, vb, V, nullptr);
    attn_kernel<<<1024, 512, 0, stream>>>(Q, K, V, io, stats, 0);

    // branch 2
    proj_mfma_kernel<<<1024, 256, 0, stream>>>(rssi2, qw, qb, Q,
                                               nullptr, nullptr, nullptr, nullptr);
    proj_mfma_kernel<<<1024, 256, 0, stream>>>(x2, kw, kb, K, vw, vb, V, nullptr);
    attn_kernel<<<1024, 512, 0, stream>>>(Q, K, V, io, stats, 1);

    bn_relu_kernel<<<16384, 256, 0, stream>>>(io, stats, gamma, beta);
}